// Round 12
// baseline (9418.183 us; speedup 1.0000x reference)
//
#include <hip/hip_runtime.h>
#include <cstdint>
#include <cstddef>

static constexpr int T_STEPS = 2048;
static constexpr int BATCH   = 32;
static constexpr int DIM     = 256;
static constexpr int NCOL    = 512;
static constexpr int RB      = 16;                              // xw1 ring depth (blocks)
static constexpr size_t M_ROWS = (size_t)T_STEPS * BATCH;   // 65536

typedef _Float16 f16x4 __attribute__((ext_vector_type(4)));
typedef _Float16 f16x8 __attribute__((ext_vector_type(8)));
typedef float    f32x4 __attribute__((ext_vector_type(4)));
struct alignas(8) H4 { _Float16 x, y, z, w; };

// ---- workspace layout (bytes) ----
static constexpr size_t XW_OFF   = 0;                           // XW f16 [65536][512] = 64 MB
static constexpr size_t A_OFF    = M_ROWS * NCOL * 2;           // Abuf f16 [65536][256] = 32 MB
                                                                // (front 8 MB reused as xw1 ring)
static constexpr size_t BLOB_OFF = A_OFF + M_ROWS * DIM * 2;    // 4 blobs x 256 KB
static constexpr size_t BLOB_ELT = (size_t)DIM * NCOL;          // 131072 f16 per blob
static constexpr size_t FLAG_OFF = BLOB_OFF + 4 * BLOB_ELT * 2; // int[64+]: flags / cons_flags
// probe scratch (inside the Abuf envelope; real ring uses first 8 MB)
static constexpr size_t RING2_OFF = A_OFF + (16u << 20);        // 8+ MB probe ring
static constexpr size_t HNSCR_OFF = A_OFF + (30u << 20);        // probe hn scratch
static constexpr size_t FLGSCR_OFF= A_OFF + (31u << 20);        // probe flags scratch

// ---------------- prep: f32 -> f16 convert (input) + flag zero ----------------
__global__ void cvt_f32_to_f16(const float* __restrict__ src, _Float16* __restrict__ dst,
                               int n4, int* __restrict__ flags) {
  if (blockIdx.x == 0 && threadIdx.x < 128) flags[threadIdx.x] = 0;  // flags + cons_flags
  int i = blockIdx.x * blockDim.x + threadIdx.x;
  if (i >= n4) return;
  float4 v = ((const float4*)src)[i];
  H4 o; o.x = (_Float16)v.x; o.y = (_Float16)v.y; o.z = (_Float16)v.z; o.w = (_Float16)v.w;
  ((H4*)dst)[i] = o;
}

// ---------------- prep: W -> MFMA B-fragment blobs (cols 0:512 of [256][768]) ----
__global__ void prep_blobs4(const float* __restrict__ w0, const float* __restrict__ w1,
                            const float* __restrict__ w2, const float* __restrict__ w3,
                            _Float16* __restrict__ blobs) {
  int gid = blockIdx.x * blockDim.x + threadIdx.x;   // < 4*131072
  int mat = gid >> 17;
  int rem = gid & 131071;
  int k = rem >> 9;        // 0..255
  int n = rem & 511;       // 0..511
  const float* src = (mat == 0) ? w0 : (mat == 1) ? w1 : (mat == 2) ? w2 : w3;
  float v = src[k * 768 + n];
  int kc = k >> 5, q = (k >> 3) & 3, j = k & 7, tn = n >> 4;
  int lane = (n & 15) + 16 * q;
  blobs[(size_t)mat * BLOB_ELT + ((size_t)(tn * 8 + kc) * 64 + lane) * 8 + j] = (_Float16)v;
}

// ---------------- GEMM: XW = A[65536,256] @ B[256,512] + bias ----------------
__global__ __launch_bounds__(256) void gemm_xw(const _Float16* __restrict__ A,
                                               const _Float16* __restrict__ blob,
                                               const float* __restrict__ bias,
                                               _Float16* __restrict__ XW) {
  int lane = threadIdx.x & 63;
  int wave = threadIdx.x >> 6;
  int wid  = blockIdx.x * 4 + wave;       // 0..8191
  int mbase = (wid >> 1) * 16;
  int nhalf = wid & 1;
  int q = lane >> 4, n15 = lane & 15;

  f32x4 acc[16];
#pragma unroll
  for (int i = 0; i < 16; i++) acc[i] = (f32x4){0.f, 0.f, 0.f, 0.f};

  const _Float16* Arow = A + (size_t)(mbase + n15) * DIM + q * 8;
#pragma unroll
  for (int kc = 0; kc < 8; kc++) {
    f16x8 af = *(const f16x8*)(Arow + kc * 32);
#pragma unroll
    for (int nt = 0; nt < 16; nt++) {
      const _Float16* bp = blob + ((size_t)((nhalf * 16 + nt) * 8 + kc) * 64 + lane) * 8;
      f16x8 bf = *(const f16x8*)bp;
      acc[nt] = __builtin_amdgcn_mfma_f32_16x16x32_f16(af, bf, acc[nt], 0, 0, 0);
    }
  }
#pragma unroll
  for (int nt = 0; nt < 16; nt++) {
    int col = nhalf * 256 + nt * 16 + n15;
    float bv = bias[col];
#pragma unroll
    for (int r = 0; r < 4; r++) {
      int m = mbase + q * 4 + r;
      XW[(size_t)m * NCOL + col] = (_Float16)(acc[nt][r] + bv);
    }
  }
}

// ---------------- fused two-layer recurrence ----------------
__device__ __forceinline__ int read_len(const void* p, int b) {
  const long long* q = (const long long*)p;
  bool ok64 = true;
  for (int i = 0; i < 32; i++) { long long v = q[i]; if (v < 0 || v > 2048) ok64 = false; }
  return ok64 ? (int)q[b] : ((const int*)p)[b];
}

__device__ __forceinline__ void gload_lds_row(const _Float16* g, _Float16* l) {
  __builtin_amdgcn_global_load_lds(
      (const __attribute__((address_space(1))) void*)g,
      (__attribute__((address_space(3))) void*)l, 16, 0, 0);
}

__device__ __forceinline__ void gate_update(float pre_h, float pre_t, bool live, float& h) {
  const float K1 = 1.442695040888963f, K2 = 2.885390081777927f;
  float phc = fminf(fmaxf(pre_h, -20.f), 20.f);
  float e1 = __builtin_amdgcn_exp2f(-K2 * phc);
  float e2 = __builtin_amdgcn_exp2f(-K1 * pre_t);
  float u1 = 1.f + e1;
  float rr = __builtin_amdgcn_rcpf(u1 * (1.f + e2));
  float ttg = (1.f - e1) * rr;
  float tg  = u1 * rr;
  float cg = 0.5f + tg * (0.250905f + tg * (-0.00432f + tg * (-0.015525f)));
  float s = ttg + h * cg;
  h = live ? s : h;
}

// ROLE=0: real fused pipeline, grid 64 (bid<32 producer, else consumer), NBLK=128.
// ROLE=1: producer-only PROBE (grid 32, scratch ring/flags, no back-pressure;
//         staging index wrapped mod 128 so 256-block runs stay in-bounds).
// ROLE=2: consumer-only PROBE (grid 32, real ring, flags pre-completed at 128:
//         WAIT threshold clamped -> polls execute but are satisfied, exactly
//         like steady-state; out1 index wrapped; outputs -> scratch).
// 256-block probes (~3-4.5 ms) outrank the 2265us fused rows in rocprof top-5.
template <int ROLE, int NBLK>
__global__ __launch_bounds__(512, 2) void recur_fused(const _Float16* __restrict__ xw0,
                                                      const _Float16* __restrict__ bwhh0,
                                                      const _Float16* __restrict__ bwhh1,
                                                      const _Float16* __restrict__ bwih1,
                                                      const float* __restrict__ b1,
                                                      const void* __restrict__ lenp,
                                                      _Float16* __restrict__ xw1ring,
                                                      float* __restrict__ out1,
                                                      float* __restrict__ hn,
                                                      int* __restrict__ flags) {
  const int bid  = blockIdx.x;
  const int tid  = threadIdx.x;
  const int w    = tid >> 6;               // wave 0..7
  const int lane = tid & 63;
  const int q = lane >> 4, l15 = lane & 15;
  int* cons_flags = flags + 64;

  __shared__ __align__(16) _Float16 hbuf[2][DIM];        // ping-pong h (1 KB)
  __shared__ __align__(16) _Float16 xbuf[2][16][NCOL];   // xw blocks (32 KB)
  __shared__ __align__(16) _Float16 sbuf[2][16][DIM];    // producer h-block (16 KB, swizzled)

  const int c0 = (2 * w) * 16 + l15;
  const int c1 = (2 * w + 1) * 16 + l15;
  const bool is_prod = (ROLE == 1) || (ROLE == 0 && bid < BATCH);
  const int b = (ROLE == 0) ? (is_prod ? bid : bid - BATCH) : bid;

  if (is_prod) {
    // ================= PRODUCER: layer 0 + x-GEMM for layer 1 =================
    const int len = read_len(lenp, b);
    f16x8 Bh[2][8], Bt[2][8];
#pragma unroll
    for (int pp = 0; pp < 2; pp++)
#pragma unroll
      for (int kc = 0; kc < 8; kc++) {
        Bh[pp][kc] = *(const f16x8*)(bwhh0 + ((size_t)((2 * w + pp) * 8 + kc) * 64 + lane) * 8);
        Bt[pp][kc] = *(const f16x8*)(bwhh0 + ((size_t)((16 + 2 * w + pp) * 8 + kc) * 64 + lane) * 8);
      }
    const float bb0 = b1[c0], bb1 = b1[c1], bb2 = b1[c0 + 256], bb3 = b1[c1 + 256];
    if (tid < DIM) hbuf[0][tid] = (_Float16)0.f;

    const _Float16* xrow = xw0 + (size_t)b * NCOL;
    const size_t xstride = (size_t)BATCH * NCOL;

    gload_lds_row(xrow + (size_t)(2 * w)     * xstride + lane * 8, &xbuf[0][2 * w][0]);
    gload_lds_row(xrow + (size_t)(2 * w + 1) * xstride + lane * 8, &xbuf[0][2 * w + 1][0]);
    asm volatile("s_waitcnt vmcnt(0)" ::: "memory");
    __syncthreads();

    float h0 = 0.f, h1 = 0.f;
    int cons_seen = 0;
    for (int tb = 0; tb < NBLK; ++tb) {
      const int buf = tb & 1;
      if (tb + 1 < NBLK) {
        const int tbn = (ROLE == 0) ? (tb + 1) : ((tb + 1) & 127);  // probe wrap
        const _Float16* gsrc = xrow + (size_t)(tbn * 16) * xstride;
        gload_lds_row(gsrc + (size_t)(2 * w)     * xstride + lane * 8, &xbuf[1 - buf][2 * w][0]);
        gload_lds_row(gsrc + (size_t)(2 * w + 1) * xstride + lane * 8, &xbuf[1 - buf][2 * w + 1][0]);
      }
#pragma unroll
      for (int ts = 0; ts < 16; ++ts) {
        const int t = tb * 16 + ts;
        const int p = ts & 1;
        const _Float16* xr = &xbuf[buf][ts][0];
        const float xh0 = (float)xr[c0],       xh1 = (float)xr[c1];
        const float xt0 = (float)xr[c0 + 256], xt1 = (float)xr[c1 + 256];

        f32x4 a0 = {0.f, 0.f, 0.f, 0.f}, a1 = a0, a2 = a0, a3 = a0;
        const _Float16* hb = &hbuf[p][q * 8];
#pragma unroll
        for (int kc = 0; kc < 8; kc++) {
          f16x8 a = *(const f16x8*)(hb + kc * 32);
          a0 = __builtin_amdgcn_mfma_f32_16x16x32_f16(a, Bh[0][kc], a0, 0, 0, 0);
          a1 = __builtin_amdgcn_mfma_f32_16x16x32_f16(a, Bh[1][kc], a1, 0, 0, 0);
          a2 = __builtin_amdgcn_mfma_f32_16x16x32_f16(a, Bt[0][kc], a2, 0, 0, 0);
          a3 = __builtin_amdgcn_mfma_f32_16x16x32_f16(a, Bt[1][kc], a3, 0, 0, 0);
        }
        const bool live = t < len;
        gate_update(a0[0] + xh0, a2[0] + xt0, live, h0);
        gate_update(a1[0] + xh1, a3[0] + xt1, live, h1);
        _Float16 s0 = (_Float16)h0, s1 = (_Float16)h1;
        if (q == 0) {
          hbuf[1 - p][c0] = s0;
          hbuf[1 - p][c1] = s1;
          char* sb = (char*)&sbuf[buf][0][0];
          const int sw = (ts & 7) << 4;
          *(_Float16*)(sb + ((ts * 512 + c0 * 2) ^ sw)) = s0;
          *(_Float16*)(sb + ((ts * 512 + c1 * 2) ^ sw)) = s1;
        }
        if (ts == 15) {
          asm volatile("s_waitcnt vmcnt(0) lgkmcnt(0)\n\ts_barrier" ::: "memory");
        } else {
          asm volatile("s_waitcnt lgkmcnt(0)\n\ts_barrier" ::: "memory");
        }
      }
      // ---- ring back-pressure (real run only) ----
      if (ROLE == 0 && tb - cons_seen >= RB - 2) {
        int it = 0;
        while ((cons_seen = __hip_atomic_load(&cons_flags[b], __ATOMIC_RELAXED,
                                              __HIP_MEMORY_SCOPE_AGENT)) < tb - (RB - 2)) {
          __builtin_amdgcn_s_sleep(2);
          if (++it > (1 << 22)) break;
        }
      }
      // ---- x-GEMM: xw1 block tb = sbuf[buf] @ Wih1 + b1 -> ring slot ----
      {
        const char* sb = (const char*)&sbuf[buf][0][0];
        f16x8 xa_[8];
#pragma unroll
        for (int kc = 0; kc < 8; kc++) {
          const int off_ = (l15 * 512 + q * 16 + kc * 64) ^ ((l15 & 7) << 4);
          xa_[kc] = *(const f16x8*)(sb + off_);
        }
        _Float16* dst = xw1ring + (size_t)(b * RB + (tb & (RB - 1))) * 16 * NCOL;
#pragma unroll
        for (int ti = 0; ti < 4; ti++) {
          const int tn = (ti < 2) ? (2 * w + ti) : (16 + 2 * w + (ti - 2));
          f32x4 acc = {0.f, 0.f, 0.f, 0.f};
#pragma unroll
          for (int kc = 0; kc < 8; kc++) {
            f16x8 bf = *(const f16x8*)(bwih1 + ((size_t)(tn * 8 + kc) * 64 + lane) * 8);
            acc = __builtin_amdgcn_mfma_f32_16x16x32_f16(xa_[kc], bf, acc, 0, 0, 0);
          }
          const int   col = (ti == 0) ? c0 : (ti == 1) ? c1 : (ti == 2) ? (c0 + 256)
                                                                        : (c1 + 256);
          const float bv  = (ti == 0) ? bb0 : (ti == 1) ? bb1 : (ti == 2) ? bb2 : bb3;
#pragma unroll
          for (int r2 = 0; r2 < 4; r2++)
            dst[(size_t)(q * 4 + r2) * NCOL + col] = (_Float16)(acc[r2] + bv);
        }
      }
      if ((tb & 3) == 3) {
        asm volatile("s_waitcnt vmcnt(0) lgkmcnt(0)\n\ts_barrier" ::: "memory");
        if (tid == 0)
          __hip_atomic_store(&flags[b], tb + 1, __ATOMIC_RELEASE, __HIP_MEMORY_SCOPE_AGENT);
      } else {
        asm volatile("s_waitcnt lgkmcnt(0)\n\ts_barrier" ::: "memory");
      }
    }
    if (q == 0) {
      hn[b * DIM + c0] = h0;
      hn[b * DIM + c1] = h1;
    }
  } else {
    // ================= CONSUMER: layer 1 (bare recurrence) =================
    const int len = read_len(lenp, b);
    f16x8 Bh[2][8], Bt[2][8];
#pragma unroll
    for (int pp = 0; pp < 2; pp++)
#pragma unroll
      for (int kc = 0; kc < 8; kc++) {
        Bh[pp][kc] = *(const f16x8*)(bwhh1 + ((size_t)((2 * w + pp) * 8 + kc) * 64 + lane) * 8);
        Bt[pp][kc] = *(const f16x8*)(bwhh1 + ((size_t)((16 + 2 * w + pp) * 8 + kc) * 64 + lane) * 8);
      }
    if (tid < DIM) hbuf[0][tid] = (_Float16)0.f;
    __syncthreads();

#define WAIT_FLAG(TH_, ACQ_)                                                             \
    {                                                                                    \
      int th_ = (TH_);                                                                   \
      if (ROLE == 2 && th_ > 128) th_ = 128;   /* probe: flags pre-completed */          \
      int it = 0;                                                                        \
      while (__hip_atomic_load(&flags[b], __ATOMIC_RELAXED, __HIP_MEMORY_SCOPE_AGENT)    \
             < th_) {                                                                    \
        __builtin_amdgcn_s_sleep(2);                                                     \
        if (++it > (1 << 22)) break;                                                     \
      }                                                                                  \
      if (ACQ_)                                                                          \
        (void)__hip_atomic_load(&flags[b], __ATOMIC_ACQUIRE, __HIP_MEMORY_SCOPE_AGENT);  \
    }

#define STAGE_RING(TB_, NB_)                                                             \
    {                                                                                    \
      const _Float16* base =                                                             \
          xw1ring + (size_t)(b * RB + ((TB_) & (RB - 1))) * 16 * NCOL;                   \
      gload_lds_row(base + (size_t)(2 * w)     * NCOL + lane * 8, &xbuf[NB_][2 * w][0]); \
      gload_lds_row(base + (size_t)(2 * w + 1) * NCOL + lane * 8, &xbuf[NB_][2 * w + 1][0]); \
    }

    float h0 = 0.f, h1 = 0.f;

    WAIT_FLAG(1, true);
    STAGE_RING(0, 0);
    asm volatile("s_waitcnt vmcnt(0)" ::: "memory");
    __syncthreads();

    for (int tb = 0; tb < NBLK; ++tb) {
      const int buf = tb & 1;
      if (tb + 1 < NBLK) {
        WAIT_FLAG(tb + 2, ((tb + 2) & 3) == 1);
        STAGE_RING(tb + 1, 1 - buf);
      }
#pragma unroll
      for (int ts = 0; ts < 16; ++ts) {
        const int t = tb * 16 + ts;
        const int p = ts & 1;
        const _Float16* xr = &xbuf[buf][ts][0];
        const float xh0 = (float)xr[c0],       xh1 = (float)xr[c1];
        const float xt0 = (float)xr[c0 + 256], xt1 = (float)xr[c1 + 256];

        f32x4 a0 = {0.f, 0.f, 0.f, 0.f}, a1 = a0, a2 = a0, a3 = a0;
        const _Float16* hb = &hbuf[p][q * 8];
#pragma unroll
        for (int kc = 0; kc < 8; kc++) {
          f16x8 a = *(const f16x8*)(hb + kc * 32);
          a0 = __builtin_amdgcn_mfma_f32_16x16x32_f16(a, Bh[0][kc], a0, 0, 0, 0);
          a1 = __builtin_amdgcn_mfma_f32_16x16x32_f16(a, Bh[1][kc], a1, 0, 0, 0);
          a2 = __builtin_amdgcn_mfma_f32_16x16x32_f16(a, Bt[0][kc], a2, 0, 0, 0);
          a3 = __builtin_amdgcn_mfma_f32_16x16x32_f16(a, Bt[1][kc], a3, 0, 0, 0);
        }
        const bool live = t < len;
        gate_update(a0[0] + xh0, a2[0] + xt0, live, h0);
        gate_update(a1[0] + xh1, a3[0] + xt1, live, h1);
        if (q == 0) {
          hbuf[1 - p][c0] = (_Float16)h0;
          hbuf[1 - p][c1] = (_Float16)h1;
          const int to = (ROLE == 2) ? (t & 2047) : t;    // probe wrap
          size_t o = ((size_t)to * BATCH + b) * DIM;
          out1[o + c0] = h0; out1[o + c1] = h1;
        }
        if (ts == 15) {
          asm volatile("s_waitcnt vmcnt(0) lgkmcnt(0)\n\ts_barrier" ::: "memory");
        } else {
          asm volatile("s_waitcnt lgkmcnt(0)\n\ts_barrier" ::: "memory");
        }
      }
      if (((tb & 3) == 3) && tid == 0)
        __hip_atomic_store(&cons_flags[b], tb + 1, __ATOMIC_RELAXED, __HIP_MEMORY_SCOPE_AGENT);
    }
#undef STAGE_RING
#undef WAIT_FLAG
    if (q == 0) {
      hn[BATCH * DIM + b * DIM + c0] = h0;
      hn[BATCH * DIM + b * DIM + c1] = h1;
    }
  }
}

extern "C" void kernel_launch(void* const* d_in, const int* in_sizes, int n_in,
                              void* d_out, int out_size, void* d_ws, size_t ws_size,
                              hipStream_t stream) {
  const float* input_ = (const float*)d_in[0];
  const void*  lenp   = d_in[1];
  const float* Wih0   = (const float*)d_in[2];
  const float* Whh0   = (const float*)d_in[3];
  const float* b0     = (const float*)d_in[4];
  const float* Wih1   = (const float*)d_in[5];
  const float* Whh1   = (const float*)d_in[6];
  const float* b1     = (const float*)d_in[7];
  float* out = (float*)d_out;
  char*  ws  = (char*)d_ws;

  _Float16* XW    = (_Float16*)(ws + XW_OFF);
  _Float16* Abuf  = (_Float16*)(ws + A_OFF);     // input f16; front 8MB reused as ring
  _Float16* blobs = (_Float16*)(ws + BLOB_OFF);  // [Wih0, Wih1, Whh0, Whh1]
  int*      flags = (int*)(ws + FLAG_OFF);
  float* hn = out + M_ROWS * DIM;                // d_out tail: h_n [2][32][256]

  // probe scratch (writes only; never feeds checked outputs)
  _Float16* ring2     = (_Float16*)(ws + RING2_OFF);
  float*    hn_scr    = (float*)(ws + HNSCR_OFF);
  int*      flags_scr = (int*)(ws + FLGSCR_OFF);
  float*    out1_scr  = (float*)(ws + XW_OFF);   // XW dead after the real dispatch

  cvt_f32_to_f16<<<16384, 256, 0, stream>>>(input_, Abuf, (int)(M_ROWS * DIM / 4), flags);
  prep_blobs4<<<2048, 256, 0, stream>>>(Wih0, Wih1, Whh0, Whh1, blobs);
  gemm_xw<<<2048, 256, 0, stream>>>(Abuf, blobs + 0 * BLOB_ELT, b0, XW);
  // ---- real fused pipeline (unchanged from r9) ----
  recur_fused<0, 128><<<2 * BATCH, 512, 0, stream>>>(XW,
                                                     blobs + 2 * BLOB_ELT,
                                                     blobs + 3 * BLOB_ELT,
                                                     blobs + 1 * BLOB_ELT,
                                                     b1, lenp, Abuf, out, hn, flags);
  // ---- PROBE B: full producer solo, 256 blocks (~3.1ms healthy / ~4.4ms sick)
  recur_fused<1, 256><<<BATCH, 512, 0, stream>>>(XW, blobs + 2 * BLOB_ELT,
                                                 blobs + 3 * BLOB_ELT, blobs + 1 * BLOB_ELT,
                                                 b1, lenp, ring2, out1_scr, hn_scr, flags_scr);
  // ---- PROBE C: full consumer solo, 256 blocks (real ring + completed flags)
  recur_fused<2, 256><<<BATCH, 512, 0, stream>>>(XW, blobs + 2 * BLOB_ELT,
                                                 blobs + 3 * BLOB_ELT, blobs + 1 * BLOB_ELT,
                                                 b1, lenp, Abuf, out1_scr, hn_scr, flags);
}

// Round 13
// 3222.311 us; speedup vs baseline: 2.9228x; 2.9228x over previous
//
#include <hip/hip_runtime.h>
#include <cstdint>
#include <cstddef>

static constexpr int T_STEPS = 2048;
static constexpr int BATCH   = 32;
static constexpr int DIM     = 256;
static constexpr int NCOL    = 512;
static constexpr int RB      = 16;                              // xw1 ring depth (blocks)
static constexpr size_t M_ROWS = (size_t)T_STEPS * BATCH;   // 65536

typedef _Float16 f16x4 __attribute__((ext_vector_type(4)));
typedef _Float16 f16x8 __attribute__((ext_vector_type(8)));
typedef float    f32x4 __attribute__((ext_vector_type(4)));
struct alignas(8) H4 { _Float16 x, y, z, w; };

// ---- workspace layout (bytes) ----
static constexpr size_t XW_OFF   = 0;                           // XW f16 [65536][512] = 64 MB
static constexpr size_t A_OFF    = M_ROWS * NCOL * 2;           // Abuf f16 (front 8 MB -> xw1 ring)
static constexpr size_t BLOB_OFF = A_OFF + M_ROWS * DIM * 2;    // 4 blobs x 256 KB
static constexpr size_t BLOB_ELT = (size_t)DIM * NCOL;          // 131072 f16 per blob
static constexpr size_t FLAG_OFF = BLOB_OFF + 4 * BLOB_ELT * 2; // int[64+]: flags / cons_flags

// ---------------- prep: f32 -> f16 convert (input) + flag zero ----------------
__global__ void cvt_f32_to_f16(const float* __restrict__ src, _Float16* __restrict__ dst,
                               int n4, int* __restrict__ flags) {
  if (blockIdx.x == 0 && threadIdx.x < 128) flags[threadIdx.x] = 0;  // flags + cons_flags
  int i = blockIdx.x * blockDim.x + threadIdx.x;
  if (i >= n4) return;
  float4 v = ((const float4*)src)[i];
  H4 o; o.x = (_Float16)v.x; o.y = (_Float16)v.y; o.z = (_Float16)v.z; o.w = (_Float16)v.w;
  ((H4*)dst)[i] = o;
}

// ---------------- prep: W -> MFMA B-fragment blobs (cols 0:512 of [256][768]) ----
__global__ void prep_blobs4(const float* __restrict__ w0, const float* __restrict__ w1,
                            const float* __restrict__ w2, const float* __restrict__ w3,
                            _Float16* __restrict__ blobs) {
  int gid = blockIdx.x * blockDim.x + threadIdx.x;   // < 4*131072
  int mat = gid >> 17;
  int rem = gid & 131071;
  int k = rem >> 9;        // 0..255
  int n = rem & 511;       // 0..511
  const float* src = (mat == 0) ? w0 : (mat == 1) ? w1 : (mat == 2) ? w2 : w3;
  float v = src[k * 768 + n];
  int kc = k >> 5, q = (k >> 3) & 3, j = k & 7, tn = n >> 4;
  int lane = (n & 15) + 16 * q;
  blobs[(size_t)mat * BLOB_ELT + ((size_t)(tn * 8 + kc) * 64 + lane) * 8 + j] = (_Float16)v;
}

// ---------------- GEMM: XW = A[65536,256] @ B[256,512] + bias ----------------
__global__ __launch_bounds__(256) void gemm_xw(const _Float16* __restrict__ A,
                                               const _Float16* __restrict__ blob,
                                               const float* __restrict__ bias,
                                               _Float16* __restrict__ XW) {
  int lane = threadIdx.x & 63;
  int wave = threadIdx.x >> 6;
  int wid  = blockIdx.x * 4 + wave;       // 0..8191
  int mbase = (wid >> 1) * 16;
  int nhalf = wid & 1;
  int q = lane >> 4, n15 = lane & 15;

  f32x4 acc[16];
#pragma unroll
  for (int i = 0; i < 16; i++) acc[i] = (f32x4){0.f, 0.f, 0.f, 0.f};

  const _Float16* Arow = A + (size_t)(mbase + n15) * DIM + q * 8;
#pragma unroll
  for (int kc = 0; kc < 8; kc++) {
    f16x8 af = *(const f16x8*)(Arow + kc * 32);
#pragma unroll
    for (int nt = 0; nt < 16; nt++) {
      const _Float16* bp = blob + ((size_t)((nhalf * 16 + nt) * 8 + kc) * 64 + lane) * 8;
      f16x8 bf = *(const f16x8*)bp;
      acc[nt] = __builtin_amdgcn_mfma_f32_16x16x32_f16(af, bf, acc[nt], 0, 0, 0);
    }
  }
#pragma unroll
  for (int nt = 0; nt < 16; nt++) {
    int col = nhalf * 256 + nt * 16 + n15;
    float bv = bias[col];
#pragma unroll
    for (int r = 0; r < 4; r++) {
      int m = mbase + q * 4 + r;
      XW[(size_t)m * NCOL + col] = (_Float16)(acc[nt][r] + bv);
    }
  }
}

// ---------------- fused two-layer recurrence ----------------
__device__ __forceinline__ int read_len(const void* p, int b) {
  const long long* q = (const long long*)p;
  bool ok64 = true;
  for (int i = 0; i < 32; i++) { long long v = q[i]; if (v < 0 || v > 2048) ok64 = false; }
  return ok64 ? (int)q[b] : ((const int*)p)[b];
}

__device__ __forceinline__ void gload_lds_row(const _Float16* g, _Float16* l) {
  __builtin_amdgcn_global_load_lds(
      (const __attribute__((address_space(1))) void*)g,
      (__attribute__((address_space(3))) void*)l, 16, 0, 0);
}

__device__ __forceinline__ void gate_update(float pre_h, float pre_t, bool live, float& h) {
  const float K1 = 1.442695040888963f, K2 = 2.885390081777927f;
  float phc = fminf(fmaxf(pre_h, -20.f), 20.f);
  float e1 = __builtin_amdgcn_exp2f(-K2 * phc);
  float e2 = __builtin_amdgcn_exp2f(-K1 * pre_t);
  float u1 = 1.f + e1;
  float rr = __builtin_amdgcn_rcpf(u1 * (1.f + e2));
  float ttg = (1.f - e1) * rr;
  float tg  = u1 * rr;
  float cg = 0.5f + tg * (0.250905f + tg * (-0.00432f + tg * (-0.015525f)));
  float s = ttg + h * cg;
  h = live ? s : h;
}

// 64 WGs x 768 threads (12 waves), 1 WG/CU.
// PRODUCER (bid<32): WAVE-SPECIALIZED (r12 probe: XGEMM-as-serial-region cost
//   the producer 660 cy/step; as separate waves its latency hides via TLP).
//   waves 0-7:  bare layer-0 recurrence (r2 structure) + swizzled sbuf publish.
//               No ring I/O, no release, no XGEMM. 16 barriers/block.
//   waves 8-11: per block tb, compute block tb-1's xw1 = sbuf[1-buf] @ Wih1 + b1
//               (8 tiles/wave), store to ring, own vmcnt(0) drain, release
//               flags[b]=tb every 4th; then execute the same 16 barriers.
//               Final block's XGEMM runs post-loop (no barriers -> no mismatch).
// CONSUMER (bid>=32): unchanged bare recurrence on waves 0-7; waves 8-11 idle
//   but execute matched barrier counts (2 prologue + 16/block).
__global__ __launch_bounds__(768, 2) void recur_fused(const _Float16* __restrict__ xw0,
                                                      const _Float16* __restrict__ bwhh0,
                                                      const _Float16* __restrict__ bwhh1,
                                                      const _Float16* __restrict__ bwih1,
                                                      const float* __restrict__ b1,
                                                      const void* __restrict__ lenp,
                                                      _Float16* __restrict__ xw1ring,
                                                      float* __restrict__ out1,
                                                      float* __restrict__ hn,
                                                      int* __restrict__ flags) {
  const int bid  = blockIdx.x;
  const int tid  = threadIdx.x;
  const int w    = tid >> 6;               // wave 0..11
  const int lane = tid & 63;
  const int q = lane >> 4, l15 = lane & 15;
  int* cons_flags = flags + 64;
  const bool recw = (w < 8);

  __shared__ __align__(16) _Float16 hbuf[2][DIM];        // ping-pong h (1 KB)
  __shared__ __align__(16) _Float16 xbuf[2][16][NCOL];   // xw blocks (32 KB)
  __shared__ __align__(16) _Float16 sbuf[2][16][DIM];    // producer h-block (16 KB, swizzled)

  const int c0 = (recw ? (2 * w) * 16 : 0) + l15;
  const int c1 = (recw ? (2 * w + 1) * 16 : 16) + l15;
  constexpr int NB = T_STEPS / 16;

  if (bid < BATCH) {
    // ================= PRODUCER =================
    const int b = bid;
    const int len = read_len(lenp, b);

    if (recw) {
      // ---------- recurrence waves 0-7 ----------
      f16x8 Bh[2][8], Bt[2][8];
#pragma unroll
      for (int pp = 0; pp < 2; pp++)
#pragma unroll
        for (int kc = 0; kc < 8; kc++) {
          Bh[pp][kc] = *(const f16x8*)(bwhh0 + ((size_t)((2 * w + pp) * 8 + kc) * 64 + lane) * 8);
          Bt[pp][kc] = *(const f16x8*)(bwhh0 + ((size_t)((16 + 2 * w + pp) * 8 + kc) * 64 + lane) * 8);
        }
      if (tid < DIM) hbuf[0][tid] = (_Float16)0.f;

      const _Float16* xrow = xw0 + (size_t)b * NCOL;
      const size_t xstride = (size_t)BATCH * NCOL;

      gload_lds_row(xrow + (size_t)(2 * w)     * xstride + lane * 8, &xbuf[0][2 * w][0]);
      gload_lds_row(xrow + (size_t)(2 * w + 1) * xstride + lane * 8, &xbuf[0][2 * w + 1][0]);
      asm volatile("s_waitcnt vmcnt(0)" ::: "memory");
      __syncthreads();                                     // P-barrier #0

      float h0 = 0.f, h1 = 0.f;
      for (int tb = 0; tb < NB; ++tb) {
        const int buf = tb & 1;
        if (tb + 1 < NB) {
          const _Float16* gsrc = xrow + (size_t)((tb + 1) * 16) * xstride;
          gload_lds_row(gsrc + (size_t)(2 * w)     * xstride + lane * 8, &xbuf[1 - buf][2 * w][0]);
          gload_lds_row(gsrc + (size_t)(2 * w + 1) * xstride + lane * 8, &xbuf[1 - buf][2 * w + 1][0]);
        }
#pragma unroll
        for (int ts = 0; ts < 16; ++ts) {
          const int t = tb * 16 + ts;
          const int p = ts & 1;
          const _Float16* xr = &xbuf[buf][ts][0];
          const float xh0 = (float)xr[c0],       xh1 = (float)xr[c1];
          const float xt0 = (float)xr[c0 + 256], xt1 = (float)xr[c1 + 256];

          f32x4 a0 = {0.f, 0.f, 0.f, 0.f}, a1 = a0, a2 = a0, a3 = a0;
          const _Float16* hb = &hbuf[p][q * 8];
#pragma unroll
          for (int kc = 0; kc < 8; kc++) {
            f16x8 a = *(const f16x8*)(hb + kc * 32);
            a0 = __builtin_amdgcn_mfma_f32_16x16x32_f16(a, Bh[0][kc], a0, 0, 0, 0);
            a1 = __builtin_amdgcn_mfma_f32_16x16x32_f16(a, Bh[1][kc], a1, 0, 0, 0);
            a2 = __builtin_amdgcn_mfma_f32_16x16x32_f16(a, Bt[0][kc], a2, 0, 0, 0);
            a3 = __builtin_amdgcn_mfma_f32_16x16x32_f16(a, Bt[1][kc], a3, 0, 0, 0);
          }
          const bool live = t < len;
          gate_update(a0[0] + xh0, a2[0] + xt0, live, h0);
          gate_update(a1[0] + xh1, a3[0] + xt1, live, h1);
          _Float16 s0 = (_Float16)h0, s1 = (_Float16)h1;
          if (q == 0) {
            hbuf[1 - p][c0] = s0;
            hbuf[1 - p][c1] = s1;
            char* sb = (char*)&sbuf[buf][0][0];
            const int sw = (ts & 7) << 4;
            *(_Float16*)(sb + ((ts * 512 + c0 * 2) ^ sw)) = s0;
            *(_Float16*)(sb + ((ts * 512 + c1 * 2) ^ sw)) = s1;
          }
          if (ts == 15) {
            asm volatile("s_waitcnt vmcnt(0) lgkmcnt(0)\n\ts_barrier" ::: "memory");
          } else {
            asm volatile("s_waitcnt lgkmcnt(0)\n\ts_barrier" ::: "memory");
          }
        }
      }
      if (q == 0) {
        hn[b * DIM + c0] = h0;
        hn[b * DIM + c1] = h1;
      }
    } else {
      // ---------- XGEMM helper waves 8-11 ----------
      const int wx = w - 8;                 // 0..3, tiles tn = wx*8 + i
      float bb[8];
#pragma unroll
      for (int i = 0; i < 8; i++) bb[i] = b1[(wx * 8 + i) * 16 + l15];
      __syncthreads();                                     // P-barrier #0

      int cons_seen = 0;
#define XGEMM_BLOCK(TBM1_)                                                               \
      {                                                                                  \
        const int pbuf_ = (TBM1_) & 1;                                                   \
        /* back-pressure: slot (TBM1_)&15 reused every 16 blocks */                      \
        if ((TBM1_) - cons_seen >= RB - 2) {                                             \
          int it = 0;                                                                    \
          while ((cons_seen = __hip_atomic_load(&cons_flags[b], __ATOMIC_RELAXED,        \
                                                __HIP_MEMORY_SCOPE_AGENT))               \
                 < (TBM1_) - (RB - 2)) {                                                 \
            __builtin_amdgcn_s_sleep(2);                                                 \
            if (++it > (1 << 22)) break;                                                 \
          }                                                                              \
        }                                                                                \
        const char* sb_ = (const char*)&sbuf[pbuf_][0][0];                               \
        f16x8 xa_[8];                                                                    \
        _Pragma("unroll")                                                                \
        for (int kc = 0; kc < 8; kc++) {                                                 \
          const int off_ = (l15 * 512 + q * 16 + kc * 64) ^ ((l15 & 7) << 4);            \
          xa_[kc] = *(const f16x8*)(sb_ + off_);                                         \
        }                                                                                \
        _Float16* dst_ = xw1ring + (size_t)(b * RB + ((TBM1_) & (RB - 1))) * 16 * NCOL;  \
        _Pragma("unroll")                                                                \
        for (int i = 0; i < 8; i++) {                                                    \
          const int tn_ = wx * 8 + i;                                                    \
          f32x4 acc = {0.f, 0.f, 0.f, 0.f};                                              \
          _Pragma("unroll")                                                              \
          for (int kc = 0; kc < 8; kc++) {                                               \
            f16x8 bf = *(const f16x8*)(bwih1 + ((size_t)(tn_ * 8 + kc) * 64 + lane) * 8);\
            acc = __builtin_amdgcn_mfma_f32_16x16x32_f16(xa_[kc], bf, acc, 0, 0, 0);     \
          }                                                                              \
          _Pragma("unroll")                                                              \
          for (int r2 = 0; r2 < 4; r2++)                                                 \
            dst_[(size_t)(q * 4 + r2) * NCOL + tn_ * 16 + l15] =                         \
                (_Float16)(acc[r2] + bb[i]);                                             \
        }                                                                                \
        asm volatile("s_waitcnt vmcnt(0)" ::: "memory");  /* own stores drained */       \
        if ((((TBM1_) & 3) == 3) && wx == 0 && lane == 0)                                \
          __hip_atomic_store(&flags[b], (TBM1_) + 1, __ATOMIC_RELEASE,                   \
                             __HIP_MEMORY_SCOPE_AGENT);                                  \
      }

      for (int tb = 0; tb < NB; ++tb) {
        if (tb > 0) XGEMM_BLOCK(tb - 1);
        for (int ts = 0; ts < 16; ++ts)
          asm volatile("s_waitcnt lgkmcnt(0)\n\ts_barrier" ::: "memory");
      }
      // tail: last block's XGEMM after all barriers (rec waves are exiting;
      // no further barriers on either path).
      XGEMM_BLOCK(NB - 1);
#undef XGEMM_BLOCK
    }
  } else {
    // ================= CONSUMER: layer 1 (bare recurrence, waves 0-7) ============
    const int b = bid - BATCH;
    const int len = read_len(lenp, b);
    const bool active = recw;
    f16x8 Bh[2][8], Bt[2][8];
    if (active) {
#pragma unroll
      for (int pp = 0; pp < 2; pp++)
#pragma unroll
        for (int kc = 0; kc < 8; kc++) {
          Bh[pp][kc] = *(const f16x8*)(bwhh1 + ((size_t)((2 * w + pp) * 8 + kc) * 64 + lane) * 8);
          Bt[pp][kc] = *(const f16x8*)(bwhh1 + ((size_t)((16 + 2 * w + pp) * 8 + kc) * 64 + lane) * 8);
        }
    }
    if (tid < DIM) hbuf[0][tid] = (_Float16)0.f;
    __syncthreads();                                       // C-barrier #0

#define WAIT_FLAG(TH_, ACQ_)                                                             \
    {                                                                                    \
      int it = 0;                                                                        \
      while (__hip_atomic_load(&flags[b], __ATOMIC_RELAXED, __HIP_MEMORY_SCOPE_AGENT)    \
             < (TH_)) {                                                                  \
        __builtin_amdgcn_s_sleep(2);                                                     \
        if (++it > (1 << 22)) break;   /* hang-breaker */                                \
      }                                                                                  \
      if (ACQ_)                                                                          \
        (void)__hip_atomic_load(&flags[b], __ATOMIC_ACQUIRE, __HIP_MEMORY_SCOPE_AGENT);  \
    }

#define STAGE_RING(TB_, NB_)                                                             \
    {                                                                                    \
      const _Float16* base =                                                             \
          xw1ring + (size_t)(b * RB + ((TB_) & (RB - 1))) * 16 * NCOL;                   \
      gload_lds_row(base + (size_t)(2 * w)     * NCOL + lane * 8, &xbuf[NB_][2 * w][0]); \
      gload_lds_row(base + (size_t)(2 * w + 1) * NCOL + lane * 8, &xbuf[NB_][2 * w + 1][0]); \
    }

    float h0 = 0.f, h1 = 0.f;

    if (active) {
      WAIT_FLAG(1, true);
      STAGE_RING(0, 0);
      asm volatile("s_waitcnt vmcnt(0)" ::: "memory");
    }
    __syncthreads();                                       // C-barrier #1

    for (int tb = 0; tb < NB; ++tb) {
      const int buf = tb & 1;
      if (active && tb + 1 < NB) {
        WAIT_FLAG(tb + 2, ((tb + 2) & 3) == 1);
        STAGE_RING(tb + 1, 1 - buf);
      }
#pragma unroll
      for (int ts = 0; ts < 16; ++ts) {
        if (active) {
          const int t = tb * 16 + ts;
          const int p = ts & 1;
          const _Float16* xr = &xbuf[buf][ts][0];
          const float xh0 = (float)xr[c0],       xh1 = (float)xr[c1];
          const float xt0 = (float)xr[c0 + 256], xt1 = (float)xr[c1 + 256];

          f32x4 a0 = {0.f, 0.f, 0.f, 0.f}, a1 = a0, a2 = a0, a3 = a0;
          const _Float16* hb = &hbuf[p][q * 8];
#pragma unroll
          for (int kc = 0; kc < 8; kc++) {
            f16x8 a = *(const f16x8*)(hb + kc * 32);
            a0 = __builtin_amdgcn_mfma_f32_16x16x32_f16(a, Bh[0][kc], a0, 0, 0, 0);
            a1 = __builtin_amdgcn_mfma_f32_16x16x32_f16(a, Bh[1][kc], a1, 0, 0, 0);
            a2 = __builtin_amdgcn_mfma_f32_16x16x32_f16(a, Bt[0][kc], a2, 0, 0, 0);
            a3 = __builtin_amdgcn_mfma_f32_16x16x32_f16(a, Bt[1][kc], a3, 0, 0, 0);
          }
          const bool live = t < len;
          gate_update(a0[0] + xh0, a2[0] + xt0, live, h0);
          gate_update(a1[0] + xh1, a3[0] + xt1, live, h1);
          if (q == 0) {
            hbuf[1 - p][c0] = (_Float16)h0;
            hbuf[1 - p][c1] = (_Float16)h1;
            size_t o = ((size_t)t * BATCH + b) * DIM;
            out1[o + c0] = h0; out1[o + c1] = h1;
          }
        }
        if (ts == 15) {
          if (active) asm volatile("s_waitcnt vmcnt(0)" ::: "memory");
          asm volatile("s_waitcnt lgkmcnt(0)\n\ts_barrier" ::: "memory");
        } else {
          asm volatile("s_waitcnt lgkmcnt(0)\n\ts_barrier" ::: "memory");
        }
      }
      if (active && ((tb & 3) == 3) && tid == 0)
        __hip_atomic_store(&cons_flags[b], tb + 1, __ATOMIC_RELAXED, __HIP_MEMORY_SCOPE_AGENT);
    }
#undef STAGE_RING
#undef WAIT_FLAG
    if (active && q == 0) {
      hn[BATCH * DIM + b * DIM + c0] = h0;
      hn[BATCH * DIM + b * DIM + c1] = h1;
    }
  }
}

extern "C" void kernel_launch(void* const* d_in, const int* in_sizes, int n_in,
                              void* d_out, int out_size, void* d_ws, size_t ws_size,
                              hipStream_t stream) {
  const float* input_ = (const float*)d_in[0];
  const void*  lenp   = d_in[1];
  const float* Wih0   = (const float*)d_in[2];
  const float* Whh0   = (const float*)d_in[3];
  const float* b0     = (const float*)d_in[4];
  const float* Wih1   = (const float*)d_in[5];
  const float* Whh1   = (const float*)d_in[6];
  const float* b1     = (const float*)d_in[7];
  float* out = (float*)d_out;
  char*  ws  = (char*)d_ws;

  _Float16* XW    = (_Float16*)(ws + XW_OFF);
  _Float16* Abuf  = (_Float16*)(ws + A_OFF);     // input f16; front 8MB reused as ring
  _Float16* blobs = (_Float16*)(ws + BLOB_OFF);  // [Wih0, Wih1, Whh0, Whh1]
  int*      flags = (int*)(ws + FLAG_OFF);
  float* hn = out + M_ROWS * DIM;                // d_out tail: h_n [2][32][256]

  cvt_f32_to_f16<<<16384, 256, 0, stream>>>(input_, Abuf, (int)(M_ROWS * DIM / 4), flags);
  prep_blobs4<<<2048, 256, 0, stream>>>(Wih0, Wih1, Whh0, Whh1, blobs);
  gemm_xw<<<2048, 256, 0, stream>>>(Abuf, blobs + 0 * BLOB_ELT, b0, XW);
  // Abuf dead after gemm_xw -> front 8 MB becomes the xw1 ring.
  recur_fused<<<2 * BATCH, 768, 0, stream>>>(XW,
                                             blobs + 2 * BLOB_ELT,   // Whh0 blob
                                             blobs + 3 * BLOB_ELT,   // Whh1 blob
                                             blobs + 1 * BLOB_ELT,   // Wih1 blob
                                             b1, lenp,
                                             Abuf,                   // xw1 ring
                                             out, hn, flags);
}

// Round 14
// 2583.041 us; speedup vs baseline: 3.6462x; 1.2475x over previous
//
#include <hip/hip_runtime.h>
#include <cstdint>
#include <cstddef>

static constexpr int T_STEPS = 2048;
static constexpr int BATCH   = 32;
static constexpr int DIM     = 256;
static constexpr int NCOL    = 512;
static constexpr int RB      = 16;                              // xw1 ring depth (blocks)
static constexpr size_t M_ROWS = (size_t)T_STEPS * BATCH;   // 65536

typedef _Float16 f16x4 __attribute__((ext_vector_type(4)));
typedef _Float16 f16x8 __attribute__((ext_vector_type(8)));
typedef float    f32x4 __attribute__((ext_vector_type(4)));
struct alignas(8) H4 { _Float16 x, y, z, w; };

// ---- workspace layout (bytes) ----
static constexpr size_t XW_OFF   = 0;                           // XW f16 [65536][512] = 64 MB
static constexpr size_t A_OFF    = M_ROWS * NCOL * 2;           // Abuf f16 (front 8 MB -> xw1 ring)
static constexpr size_t BLOB_OFF = A_OFF + M_ROWS * DIM * 2;    // 4 blobs x 256 KB
static constexpr size_t BLOB_ELT = (size_t)DIM * NCOL;          // 131072 f16 per blob
static constexpr size_t FLAG_OFF = BLOB_OFF + 4 * BLOB_ELT * 2; // int[64+]: flags / cons_flags

// ---------------- prep: f32 -> f16 convert (input) + flag zero ----------------
__global__ void cvt_f32_to_f16(const float* __restrict__ src, _Float16* __restrict__ dst,
                               int n4, int* __restrict__ flags) {
  if (blockIdx.x == 0 && threadIdx.x < 128) flags[threadIdx.x] = 0;  // flags + cons_flags
  int i = blockIdx.x * blockDim.x + threadIdx.x;
  if (i >= n4) return;
  float4 v = ((const float4*)src)[i];
  H4 o; o.x = (_Float16)v.x; o.y = (_Float16)v.y; o.z = (_Float16)v.z; o.w = (_Float16)v.w;
  ((H4*)dst)[i] = o;
}

// ---------------- prep: W -> MFMA B-fragment blobs (cols 0:512 of [256][768]) ----
__global__ void prep_blobs4(const float* __restrict__ w0, const float* __restrict__ w1,
                            const float* __restrict__ w2, const float* __restrict__ w3,
                            _Float16* __restrict__ blobs) {
  int gid = blockIdx.x * blockDim.x + threadIdx.x;   // < 4*131072
  int mat = gid >> 17;
  int rem = gid & 131071;
  int k = rem >> 9;        // 0..255
  int n = rem & 511;       // 0..511
  const float* src = (mat == 0) ? w0 : (mat == 1) ? w1 : (mat == 2) ? w2 : w3;
  float v = src[k * 768 + n];
  int kc = k >> 5, q = (k >> 3) & 3, j = k & 7, tn = n >> 4;
  int lane = (n & 15) + 16 * q;
  blobs[(size_t)mat * BLOB_ELT + ((size_t)(tn * 8 + kc) * 64 + lane) * 8 + j] = (_Float16)v;
}

// ---------------- GEMM: XW = A[65536,256] @ B[256,512] + bias ----------------
__global__ __launch_bounds__(256) void gemm_xw(const _Float16* __restrict__ A,
                                               const _Float16* __restrict__ blob,
                                               const float* __restrict__ bias,
                                               _Float16* __restrict__ XW) {
  int lane = threadIdx.x & 63;
  int wave = threadIdx.x >> 6;
  int wid  = blockIdx.x * 4 + wave;       // 0..8191
  int mbase = (wid >> 1) * 16;
  int nhalf = wid & 1;
  int q = lane >> 4, n15 = lane & 15;

  f32x4 acc[16];
#pragma unroll
  for (int i = 0; i < 16; i++) acc[i] = (f32x4){0.f, 0.f, 0.f, 0.f};

  const _Float16* Arow = A + (size_t)(mbase + n15) * DIM + q * 8;
#pragma unroll
  for (int kc = 0; kc < 8; kc++) {
    f16x8 af = *(const f16x8*)(Arow + kc * 32);
#pragma unroll
    for (int nt = 0; nt < 16; nt++) {
      const _Float16* bp = blob + ((size_t)((nhalf * 16 + nt) * 8 + kc) * 64 + lane) * 8;
      f16x8 bf = *(const f16x8*)bp;
      acc[nt] = __builtin_amdgcn_mfma_f32_16x16x32_f16(af, bf, acc[nt], 0, 0, 0);
    }
  }
#pragma unroll
  for (int nt = 0; nt < 16; nt++) {
    int col = nhalf * 256 + nt * 16 + n15;
    float bv = bias[col];
#pragma unroll
    for (int r = 0; r < 4; r++) {
      int m = mbase + q * 4 + r;
      XW[(size_t)m * NCOL + col] = (_Float16)(acc[nt][r] + bv);
    }
  }
}

// ---------------- fused two-layer recurrence ----------------
__device__ __forceinline__ int read_len(const void* p, int b) {
  const long long* q = (const long long*)p;
  bool ok64 = true;
  for (int i = 0; i < 32; i++) { long long v = q[i]; if (v < 0 || v > 2048) ok64 = false; }
  return ok64 ? (int)q[b] : ((const int*)p)[b];
}

__device__ __forceinline__ void gload_lds_row(const _Float16* g, _Float16* l) {
  __builtin_amdgcn_global_load_lds(
      (const __attribute__((address_space(1))) void*)g,
      (__attribute__((address_space(3))) void*)l, 16, 0, 0);
}

__device__ __forceinline__ void gate_update(float pre_h, float pre_t, bool live, float& h) {
  const float K1 = 1.442695040888963f, K2 = 2.885390081777927f;
  float phc = fminf(fmaxf(pre_h, -20.f), 20.f);
  float e1 = __builtin_amdgcn_exp2f(-K2 * phc);
  float e2 = __builtin_amdgcn_exp2f(-K1 * pre_t);
  float u1 = 1.f + e1;
  float rr = __builtin_amdgcn_rcpf(u1 * (1.f + e2));
  float ttg = (1.f - e1) * rr;
  float tg  = u1 * rr;
  float cg = 0.5f + tg * (0.250905f + tg * (-0.00432f + tg * (-0.015525f)));
  float s = ttg + h * cg;
  h = live ? s : h;
}

// 64 WGs x 512 threads (r9 skeleton; r13's 12-wave split reverted).
// PRODUCER (bid<32): layer-0 recurrence with the block-(tb-1) x-GEMM SLICED
//   into 16 per-step chunks (r13 lesson: a monolithic XGEMM region between
//   WG barriers gates step 0 of every block; 2 loads + 2 MFMAs per step
//   dissolve into each 1676-cy step region instead).
//   - block start (tb>0): read xa_[8] from sbuf[1-buf] (prev block's h).
//   - step ts: group g=ts>>2 -> tile tn; load 2 bwih1 frags (L2-hot),
//     2 MFMAs into xacc; at ts%4==3 store 4 f16 to ring slot (tb-1)&15.
//   - stores drained by the existing ts==15 vmcnt(0); release flags[b]=tb
//     at block-end when tb%4==0 (same flag values 4,8..128 as r9).
//   - tail: block NB-1's x-GEMM once, serial, then final release.
// CONSUMER (bid>=32): byte-identical to r9 (passed 3x).
__global__ __launch_bounds__(512, 2) void recur_fused(const _Float16* __restrict__ xw0,
                                                      const _Float16* __restrict__ bwhh0,
                                                      const _Float16* __restrict__ bwhh1,
                                                      const _Float16* __restrict__ bwih1,
                                                      const float* __restrict__ b1,
                                                      const void* __restrict__ lenp,
                                                      _Float16* __restrict__ xw1ring,
                                                      float* __restrict__ out1,
                                                      float* __restrict__ hn,
                                                      int* __restrict__ flags) {
  const int bid  = blockIdx.x;
  const int tid  = threadIdx.x;
  const int w    = tid >> 6;               // wave 0..7
  const int lane = tid & 63;
  const int q = lane >> 4, l15 = lane & 15;
  int* cons_flags = flags + 64;

  __shared__ __align__(16) _Float16 hbuf[2][DIM];        // ping-pong h (1 KB)
  __shared__ __align__(16) _Float16 xbuf[2][16][NCOL];   // xw blocks (32 KB)
  __shared__ __align__(16) _Float16 sbuf[2][16][DIM];    // producer h-block (16 KB, swizzled)

  const int c0 = (2 * w) * 16 + l15;
  const int c1 = (2 * w + 1) * 16 + l15;
  constexpr int NB = T_STEPS / 16;

  if (bid < BATCH) {
    // ================= PRODUCER =================
    const int b = bid;
    const int len = read_len(lenp, b);
    f16x8 Bh[2][8], Bt[2][8];
#pragma unroll
    for (int pp = 0; pp < 2; pp++)
#pragma unroll
      for (int kc = 0; kc < 8; kc++) {
        Bh[pp][kc] = *(const f16x8*)(bwhh0 + ((size_t)((2 * w + pp) * 8 + kc) * 64 + lane) * 8);
        Bt[pp][kc] = *(const f16x8*)(bwhh0 + ((size_t)((16 + 2 * w + pp) * 8 + kc) * 64 + lane) * 8);
      }
    const float bb0 = b1[c0], bb1 = b1[c1], bb2 = b1[c0 + 256], bb3 = b1[c1 + 256];
    if (tid < DIM) hbuf[0][tid] = (_Float16)0.f;

    const _Float16* xrow = xw0 + (size_t)b * NCOL;
    const size_t xstride = (size_t)BATCH * NCOL;

    gload_lds_row(xrow + (size_t)(2 * w)     * xstride + lane * 8, &xbuf[0][2 * w][0]);
    gload_lds_row(xrow + (size_t)(2 * w + 1) * xstride + lane * 8, &xbuf[0][2 * w + 1][0]);
    asm volatile("s_waitcnt vmcnt(0)" ::: "memory");
    __syncthreads();

    float h0 = 0.f, h1 = 0.f;
    int cons_seen = 0;
    f32x4 xacc = {0.f, 0.f, 0.f, 0.f};
    for (int tb = 0; tb < NB; ++tb) {
      const int buf = tb & 1;
      const bool do_x = (tb > 0);
      // back-pressure for ring slot (tb-1)&15 (steady state: never trips)
      if (do_x && (tb - 1) - cons_seen >= RB - 2) {
        int it = 0;
        while ((cons_seen = __hip_atomic_load(&cons_flags[b], __ATOMIC_RELAXED,
                                              __HIP_MEMORY_SCOPE_AGENT)) < (tb - 1) - (RB - 2)) {
          __builtin_amdgcn_s_sleep(2);
          if (++it > (1 << 22)) break;
        }
      }
      // prev-block h fragments for the sliced x-GEMM
      f16x8 xa_[8];
      if (do_x) {
        const char* sb_ = (const char*)&sbuf[1 - buf][0][0];
#pragma unroll
        for (int kc = 0; kc < 8; kc++) {
          const int off_ = (l15 * 512 + q * 16 + kc * 64) ^ ((l15 & 7) << 4);
          xa_[kc] = *(const f16x8*)(sb_ + off_);
        }
      }
      _Float16* xdst = xw1ring + (size_t)(b * RB + ((tb - 1) & (RB - 1))) * 16 * NCOL;
      if (tb + 1 < NB) {
        const _Float16* gsrc = xrow + (size_t)((tb + 1) * 16) * xstride;
        gload_lds_row(gsrc + (size_t)(2 * w)     * xstride + lane * 8, &xbuf[1 - buf][2 * w][0]);
        gload_lds_row(gsrc + (size_t)(2 * w + 1) * xstride + lane * 8, &xbuf[1 - buf][2 * w + 1][0]);
      }
#pragma unroll
      for (int ts = 0; ts < 16; ++ts) {
        const int t = tb * 16 + ts;
        const int p = ts & 1;
        const _Float16* xr = &xbuf[buf][ts][0];
        const float xh0 = (float)xr[c0],       xh1 = (float)xr[c1];
        const float xt0 = (float)xr[c0 + 256], xt1 = (float)xr[c1 + 256];

        f32x4 a0 = {0.f, 0.f, 0.f, 0.f}, a1 = a0, a2 = a0, a3 = a0;
        const _Float16* hb = &hbuf[p][q * 8];
#pragma unroll
        for (int kc = 0; kc < 8; kc++) {
          f16x8 a = *(const f16x8*)(hb + kc * 32);
          a0 = __builtin_amdgcn_mfma_f32_16x16x32_f16(a, Bh[0][kc], a0, 0, 0, 0);
          a1 = __builtin_amdgcn_mfma_f32_16x16x32_f16(a, Bh[1][kc], a1, 0, 0, 0);
          a2 = __builtin_amdgcn_mfma_f32_16x16x32_f16(a, Bt[0][kc], a2, 0, 0, 0);
          a3 = __builtin_amdgcn_mfma_f32_16x16x32_f16(a, Bt[1][kc], a3, 0, 0, 0);
        }
        // ---- sliced x-GEMM chunk: 2 frag loads + 2 MFMAs (block tb-1) ----
        if (do_x) {
          const int g  = ts >> 2;             // 0..3 (compile-time per unrolled ts)
          const int j2 = (ts & 3) * 2;
          const int tn = (g < 2) ? (2 * w + g) : (16 + 2 * w + (g - 2));
          f16x8 bf0 = *(const f16x8*)(bwih1 + ((size_t)(tn * 8 + j2) * 64 + lane) * 8);
          f16x8 bf1 = *(const f16x8*)(bwih1 + ((size_t)(tn * 8 + j2 + 1) * 64 + lane) * 8);
          if ((ts & 3) == 0) xacc = (f32x4){0.f, 0.f, 0.f, 0.f};
          xacc = __builtin_amdgcn_mfma_f32_16x16x32_f16(xa_[j2],     bf0, xacc, 0, 0, 0);
          xacc = __builtin_amdgcn_mfma_f32_16x16x32_f16(xa_[j2 + 1], bf1, xacc, 0, 0, 0);
          if ((ts & 3) == 3) {
            const int   col = (g == 0) ? c0 : (g == 1) ? c1 : (g == 2) ? (c0 + 256) : (c1 + 256);
            const float bv  = (g == 0) ? bb0 : (g == 1) ? bb1 : (g == 2) ? bb2 : bb3;
#pragma unroll
            for (int r2 = 0; r2 < 4; r2++)
              xdst[(size_t)(q * 4 + r2) * NCOL + col] = (_Float16)(xacc[r2] + bv);
          }
        }
        const bool live = t < len;
        gate_update(a0[0] + xh0, a2[0] + xt0, live, h0);
        gate_update(a1[0] + xh1, a3[0] + xt1, live, h1);
        _Float16 s0 = (_Float16)h0, s1 = (_Float16)h1;
        if (q == 0) {
          hbuf[1 - p][c0] = s0;
          hbuf[1 - p][c1] = s1;
          char* sb = (char*)&sbuf[buf][0][0];
          const int sw = (ts & 7) << 4;
          *(_Float16*)(sb + ((ts * 512 + c0 * 2) ^ sw)) = s0;
          *(_Float16*)(sb + ((ts * 512 + c1 * 2) ^ sw)) = s1;
        }
        if (ts == 15) {
          // drains staging loads AND this block's ring stores (all waves).
          asm volatile("s_waitcnt vmcnt(0) lgkmcnt(0)\n\ts_barrier" ::: "memory");
        } else {
          asm volatile("s_waitcnt lgkmcnt(0)\n\ts_barrier" ::: "memory");
        }
      }
      // publish: at end of block tb (tb%4==0), xw1 blocks 0..tb-1 are written
      // and drained (each wave's ts==15 vmcnt(0) precedes the barrier).
      if (((tb & 3) == 0) && tb > 0 && tid == 0)
        __hip_atomic_store(&flags[b], tb, __ATOMIC_RELEASE, __HIP_MEMORY_SCOPE_AGENT);
    }
    // ---- tail: block NB-1's x-GEMM (serial, once) + final release ----
    {
      const char* sb_ = (const char*)&sbuf[(NB - 1) & 1][0][0];
      f16x8 xa_[8];
#pragma unroll
      for (int kc = 0; kc < 8; kc++) {
        const int off_ = (l15 * 512 + q * 16 + kc * 64) ^ ((l15 & 7) << 4);
        xa_[kc] = *(const f16x8*)(sb_ + off_);
      }
      _Float16* dst = xw1ring + (size_t)(b * RB + ((NB - 1) & (RB - 1))) * 16 * NCOL;
#pragma unroll
      for (int ti = 0; ti < 4; ti++) {
        const int tn = (ti < 2) ? (2 * w + ti) : (16 + 2 * w + (ti - 2));
        f32x4 acc = {0.f, 0.f, 0.f, 0.f};
#pragma unroll
        for (int kc = 0; kc < 8; kc++) {
          f16x8 bf = *(const f16x8*)(bwih1 + ((size_t)(tn * 8 + kc) * 64 + lane) * 8);
          acc = __builtin_amdgcn_mfma_f32_16x16x32_f16(xa_[kc], bf, acc, 0, 0, 0);
        }
        const int   col = (ti == 0) ? c0 : (ti == 1) ? c1 : (ti == 2) ? (c0 + 256) : (c1 + 256);
        const float bv  = (ti == 0) ? bb0 : (ti == 1) ? bb1 : (ti == 2) ? bb2 : bb3;
#pragma unroll
        for (int r2 = 0; r2 < 4; r2++)
          dst[(size_t)(q * 4 + r2) * NCOL + col] = (_Float16)(acc[r2] + bv);
      }
      asm volatile("s_waitcnt vmcnt(0)" ::: "memory");
      __syncthreads();                      // all producer waves drained
      if (tid == 0)
        __hip_atomic_store(&flags[b], NB, __ATOMIC_RELEASE, __HIP_MEMORY_SCOPE_AGENT);
    }
    if (q == 0) {
      hn[b * DIM + c0] = h0;
      hn[b * DIM + c1] = h1;
    }
  } else {
    // ================= CONSUMER: layer 1 (bare recurrence; r9-identical) ==========
    const int b = bid - BATCH;
    const int len = read_len(lenp, b);
    f16x8 Bh[2][8], Bt[2][8];
#pragma unroll
    for (int pp = 0; pp < 2; pp++)
#pragma unroll
      for (int kc = 0; kc < 8; kc++) {
        Bh[pp][kc] = *(const f16x8*)(bwhh1 + ((size_t)((2 * w + pp) * 8 + kc) * 64 + lane) * 8);
        Bt[pp][kc] = *(const f16x8*)(bwhh1 + ((size_t)((16 + 2 * w + pp) * 8 + kc) * 64 + lane) * 8);
      }
    if (tid < DIM) hbuf[0][tid] = (_Float16)0.f;
    __syncthreads();

#define WAIT_FLAG(TH_, ACQ_)                                                             \
    {                                                                                    \
      int it = 0;                                                                        \
      while (__hip_atomic_load(&flags[b], __ATOMIC_RELAXED, __HIP_MEMORY_SCOPE_AGENT)    \
             < (TH_)) {                                                                  \
        __builtin_amdgcn_s_sleep(2);                                                     \
        if (++it > (1 << 22)) break;   /* hang-breaker */                                \
      }                                                                                  \
      if (ACQ_)                                                                          \
        (void)__hip_atomic_load(&flags[b], __ATOMIC_ACQUIRE, __HIP_MEMORY_SCOPE_AGENT);  \
    }

#define STAGE_RING(TB_, NB_)                                                             \
    {                                                                                    \
      const _Float16* base =                                                             \
          xw1ring + (size_t)(b * RB + ((TB_) & (RB - 1))) * 16 * NCOL;                   \
      gload_lds_row(base + (size_t)(2 * w)     * NCOL + lane * 8, &xbuf[NB_][2 * w][0]); \
      gload_lds_row(base + (size_t)(2 * w + 1) * NCOL + lane * 8, &xbuf[NB_][2 * w + 1][0]); \
    }

    float h0 = 0.f, h1 = 0.f;

    WAIT_FLAG(1, true);
    STAGE_RING(0, 0);
    asm volatile("s_waitcnt vmcnt(0)" ::: "memory");
    __syncthreads();

    for (int tb = 0; tb < NB; ++tb) {
      const int buf = tb & 1;
      if (tb + 1 < NB) {
        WAIT_FLAG(tb + 2, ((tb + 2) & 3) == 1);
        STAGE_RING(tb + 1, 1 - buf);
      }
#pragma unroll
      for (int ts = 0; ts < 16; ++ts) {
        const int t = tb * 16 + ts;
        const int p = ts & 1;
        const _Float16* xr = &xbuf[buf][ts][0];
        const float xh0 = (float)xr[c0],       xh1 = (float)xr[c1];
        const float xt0 = (float)xr[c0 + 256], xt1 = (float)xr[c1 + 256];

        f32x4 a0 = {0.f, 0.f, 0.f, 0.f}, a1 = a0, a2 = a0, a3 = a0;
        const _Float16* hb = &hbuf[p][q * 8];
#pragma unroll
        for (int kc = 0; kc < 8; kc++) {
          f16x8 a = *(const f16x8*)(hb + kc * 32);
          a0 = __builtin_amdgcn_mfma_f32_16x16x32_f16(a, Bh[0][kc], a0, 0, 0, 0);
          a1 = __builtin_amdgcn_mfma_f32_16x16x32_f16(a, Bh[1][kc], a1, 0, 0, 0);
          a2 = __builtin_amdgcn_mfma_f32_16x16x32_f16(a, Bt[0][kc], a2, 0, 0, 0);
          a3 = __builtin_amdgcn_mfma_f32_16x16x32_f16(a, Bt[1][kc], a3, 0, 0, 0);
        }
        const bool live = t < len;
        gate_update(a0[0] + xh0, a2[0] + xt0, live, h0);
        gate_update(a1[0] + xh1, a3[0] + xt1, live, h1);
        if (q == 0) {
          hbuf[1 - p][c0] = (_Float16)h0;
          hbuf[1 - p][c1] = (_Float16)h1;
          size_t o = ((size_t)t * BATCH + b) * DIM;
          out1[o + c0] = h0; out1[o + c1] = h1;
        }
        if (ts == 15) {
          asm volatile("s_waitcnt vmcnt(0) lgkmcnt(0)\n\ts_barrier" ::: "memory");
        } else {
          asm volatile("s_waitcnt lgkmcnt(0)\n\ts_barrier" ::: "memory");
        }
      }
      if (((tb & 3) == 3) && tid == 0)
        __hip_atomic_store(&cons_flags[b], tb + 1, __ATOMIC_RELAXED, __HIP_MEMORY_SCOPE_AGENT);
    }
#undef STAGE_RING
#undef WAIT_FLAG
    if (q == 0) {
      hn[BATCH * DIM + b * DIM + c0] = h0;
      hn[BATCH * DIM + b * DIM + c1] = h1;
    }
  }
}

extern "C" void kernel_launch(void* const* d_in, const int* in_sizes, int n_in,
                              void* d_out, int out_size, void* d_ws, size_t ws_size,
                              hipStream_t stream) {
  const float* input_ = (const float*)d_in[0];
  const void*  lenp   = d_in[1];
  const float* Wih0   = (const float*)d_in[2];
  const float* Whh0   = (const float*)d_in[3];
  const float* b0     = (const float*)d_in[4];
  const float* Wih1   = (const float*)d_in[5];
  const float* Whh1   = (const float*)d_in[6];
  const float* b1     = (const float*)d_in[7];
  float* out = (float*)d_out;
  char*  ws  = (char*)d_ws;

  _Float16* XW    = (_Float16*)(ws + XW_OFF);
  _Float16* Abuf  = (_Float16*)(ws + A_OFF);     // input f16; front 8MB reused as ring
  _Float16* blobs = (_Float16*)(ws + BLOB_OFF);  // [Wih0, Wih1, Whh0, Whh1]
  int*      flags = (int*)(ws + FLAG_OFF);
  float* hn = out + M_ROWS * DIM;                // d_out tail: h_n [2][32][256]

  cvt_f32_to_f16<<<16384, 256, 0, stream>>>(input_, Abuf, (int)(M_ROWS * DIM / 4), flags);
  prep_blobs4<<<2048, 256, 0, stream>>>(Wih0, Wih1, Whh0, Whh1, blobs);
  gemm_xw<<<2048, 256, 0, stream>>>(Abuf, blobs + 0 * BLOB_ELT, b0, XW);
  // Abuf dead after gemm_xw -> front 8 MB becomes the xw1 ring.
  recur_fused<<<2 * BATCH, 512, 0, stream>>>(XW,
                                             blobs + 2 * BLOB_ELT,   // Whh0 blob
                                             blobs + 3 * BLOB_ELT,   // Whh1 blob
                                             blobs + 1 * BLOB_ELT,   // Wih1 blob
                                             b1, lenp,
                                             Abuf,                   // xw1 ring
                                             out, hn, flags);
}